// Round 22
// baseline (3115.056 us; speedup 1.0000x reference)
//
#include <hip/hip_runtime.h>
#include <hip/hip_bf16.h>

// TSGCN: GCN -> GRU(4096->256) -> GRU(256->256) -> FC head
// B=32 S=512 N=64 F=16 G=64 H=256.
// R22 = R21 + pipelined GRU0/gemm1/GRU1 in ONE 64-block kernel:
//   blocks 0-31: GRU0 (R21 math) + per-batch progress publish every 16 steps
//                (full __syncthreads drain -> release store, AGENT scope).
//   blocks 32-63: GRU1 in 4 groups of 128 steps; each group: acquire-spin on
//                GRU0 progress, inline gemm tile (128x768, K=256; exact
//                k_gemm_lds fragment math & term order), barrier, 128 steps.
// Cross-block release/acquire flag pattern validated on-chip by R0.
// gi1 aliased onto dead seq region (CHUNK>=4096 guard; serial fallback kept).

#define EPS_BN 1e-5f

typedef float f32x4 __attribute__((ext_vector_type(4)));
typedef unsigned u32x4v __attribute__((ext_vector_type(4)));

#define GRU_BARRIER() do {                       \
    asm volatile("" ::: "memory");               \
    asm volatile("s_waitcnt lgkmcnt(0)");        \
    __builtin_amdgcn_s_barrier();                \
    asm volatile("" ::: "memory");               \
  } while (0)

#define MFMA_VV(c, a, b) asm volatile("v_mfma_f32_16x16x32_f16 %0, %1, %2, %0" \
                                      : "+v"(c) : "v"(a), "v"(b))
#define MFMA_A(c, a, b) asm volatile("v_mfma_f32_16x16x32_f16 %0, %1, %2, %0" \
                                     : "+v"(c) : "v"(a), "a"(b))

#define GLOAD_LDS16(gp, lp) \
  __builtin_amdgcn_global_load_lds( \
      (const __attribute__((address_space(1))) void*)(gp), \
      (__attribute__((address_space(3))) void*)(lp), 16, 0, 0)

// ---------------------------------------------------- fp32 -> f16 hi/lo split
__global__ void k_split16(const float* __restrict__ src,
                          _Float16* __restrict__ hi, _Float16* __restrict__ lo,
                          int n) {
  int i = blockIdx.x * 256 + threadIdx.x;
  if (i >= n) return;
  float v = src[i];
  _Float16 h = (_Float16)v;
  hi[i] = h;
  lo[i] = (_Float16)(v - (float)h);
}

// ---------------------------------------------- pack Whh into MFMA B-fragments
__global__ void k_pack_frag(const float* __restrict__ whh, uint4* __restrict__ wp) {
  int tid = blockIdx.x * 256 + threadIdx.x;
  if (tid >= 24576) return;
  int l = tid & 63;
  int rest = tid >> 6;
  int ks = rest & 7; rest >>= 3;
  int nt = rest % 6;
  int w  = rest / 6;
  int n  = 16 * w + 128 * nt + (l & 15);
  int kb = ks * 32 + (l >> 4) * 8;
  const float* src = whh + (size_t)n * 256 + kb;
  unsigned dw[4];
#pragma unroll
  for (int d = 0; d < 4; ++d) {
    unsigned short lo = __builtin_bit_cast(unsigned short, (_Float16)src[2 * d]);
    unsigned short hi = __builtin_bit_cast(unsigned short, (_Float16)src[2 * d + 1]);
    dw[d] = (unsigned)lo | ((unsigned)hi << 16);
  }
  wp[tid] = make_uint4(dw[0], dw[1], dw[2], dw[3]);
}

// ------------------------------------- pack adj (A-frags) + W1 (B-frags) hi/lo
__global__ void k_pack_gcn(const float* __restrict__ adj, const float* __restrict__ W1,
                           uint4* __restrict__ adjFh, uint4* __restrict__ adjFl,
                           uint4* __restrict__ w1Fh, uint4* __restrict__ w1Fl) {
  int tid = blockIdx.x * 256 + threadIdx.x;
  if (tid >= 1024) return;
  int l = tid & 63;
  int fi = (tid >> 6) & 7;
  bool isW1 = tid >= 512;
  int tile = fi >> 1, ks = fi & 1;
  int rc = tile * 16 + (l & 15);
  int kb = ks * 32 + (l >> 4) * 8;
  unsigned hdw[4], ldw[4];
#pragma unroll
  for (int d2 = 0; d2 < 4; ++d2) {
    unsigned short hv2[2], lv2[2];
#pragma unroll
    for (int e = 0; e < 2; ++e) {
      int k = kb + 2 * d2 + e;
      float v = isW1 ? W1[k * 64 + rc] : adj[rc * 64 + k];
      _Float16 hv = (_Float16)v;
      _Float16 lv = (_Float16)(v - (float)hv);
      hv2[e] = __builtin_bit_cast(unsigned short, hv);
      lv2[e] = __builtin_bit_cast(unsigned short, lv);
    }
    hdw[d2] = (unsigned)hv2[0] | ((unsigned)hv2[1] << 16);
    ldw[d2] = (unsigned)lv2[0] | ((unsigned)lv2[1] << 16);
  }
  uint4 hq = make_uint4(hdw[0], hdw[1], hdw[2], hdw[3]);
  uint4 lq = make_uint4(ldw[0], ldw[1], ldw[2], ldw[3]);
  if (isW1) { w1Fh[fi * 64 + l] = hq; w1Fl[fi * 64 + l] = lq; }
  else      { adjFh[fi * 64 + l] = hq; adjFl[fi * 64 + l] = lq; }
}

static __device__ __forceinline__ unsigned pk2(float a, float b, float& ra, float& rb) {
  _Float16 ha = (_Float16)a, hb = (_Float16)b;
  ra = a - (float)ha; rb = b - (float)hb;
  return (unsigned)__builtin_bit_cast(unsigned short, ha) |
         ((unsigned)__builtin_bit_cast(unsigned short, hb) << 16);
}
static __device__ __forceinline__ unsigned pk2r(float a, float b) {
  _Float16 ha = (_Float16)a, hb = (_Float16)b;
  return (unsigned)__builtin_bit_cast(unsigned short, ha) |
         ((unsigned)__builtin_bit_cast(unsigned short, hb) << 16);
}

// ------------------------------------------------------------- fused GCN
// (R19/R21 proven version, unchanged)
__global__ __launch_bounds__(256) void k_gcn(
    const float* __restrict__ x,
    const float* __restrict__ adj,
    const float* __restrict__ W0, const float* __restrict__ b0,
    const uint4* __restrict__ adjFh, const uint4* __restrict__ adjFl,
    const uint4* __restrict__ w1Fh, const uint4* __restrict__ w1Fl,
    const float* __restrict__ b1,
    const float* __restrict__ bn_g, const float* __restrict__ bn_b,
    const float* __restrict__ bn_m, const float* __restrict__ bn_v,
    _Float16* __restrict__ seqh, _Float16* __restrict__ seql, int base)
{
  __shared__ float AsT[4096];
  __shared__ float Xs[1024];
  __shared__ __align__(16) _Float16 Hsh[64 * 72], Hsl[64 * 72];
  __shared__ __align__(16) _Float16 Qth[64 * 72], Qtl[64 * 72];
  __shared__ float bnm_s[64], bns_s[64], bnb_s[64];

  const int t = threadIdx.x;
  const int lane = t & 63;
  const int w = t >> 6;
  const int m = base + blockIdx.x;

  {
    const float4* a4 = (const float4*)adj;
#pragma unroll
    for (int p = 0; p < 4; ++p) {
      const int idx = t + 256 * p;
      const float4 av = a4[idx];
      const int u = idx >> 4, v4 = (idx & 15) * 4;
      AsT[(v4 + 0) * 64 + u] = av.x;
      AsT[(v4 + 1) * 64 + u] = av.y;
      AsT[(v4 + 2) * 64 + u] = av.z;
      AsT[(v4 + 3) * 64 + u] = av.w;
    }
    ((float4*)Xs)[t] = ((const float4*)(x + (size_t)m * 1024))[t];
  }
  if (t < 64) {
    bns_s[t] = rsqrtf(bn_v[t] + EPS_BN) * bn_g[t];
    bnm_s[t] = bn_m[t];
    bnb_s[t] = bn_b[t];
  }
  float w0r[16];
#pragma unroll
  for (int f = 0; f < 16; ++f) w0r[f] = W0[f * 64 + lane];
  const float b0v = b0[lane];
  __syncthreads();

  float axr[4] = {0.f, 0.f, 0.f, 0.f};
  const int f0 = w * 4;
#pragma unroll
  for (int v = 0; v < 64; ++v) {
    const float a_vu = AsT[v * 64 + lane];
    const float4 xv = *(const float4*)&Xs[v * 16 + f0];
    axr[0] = fmaf(a_vu, xv.x, axr[0]);
    axr[1] = fmaf(a_vu, xv.y, axr[1]);
    axr[2] = fmaf(a_vu, xv.z, axr[2]);
    axr[3] = fmaf(a_vu, xv.w, axr[3]);
  }
  __syncthreads();
#pragma unroll
  for (int j = 0; j < 4; ++j) Xs[lane * 16 + f0 + j] = axr[j];
  __syncthreads();

#pragma unroll
  for (int uu = 0; uu < 16; ++uu) {
    const int u = w * 16 + uu;
    float acc = 0.f;
#pragma unroll
    for (int f = 0; f < 16; ++f) acc += Xs[u * 16 + f] * w0r[f];
    float h1 = fmaxf(acc + b0v, 0.f);
    h1 = (h1 - bnm_s[u]) * bns_s[u] + bnb_s[u];
    const _Float16 hh = (_Float16)h1;
    Hsh[u * 72 + lane] = hh;
    Hsl[u * 72 + lane] = (_Float16)(h1 - (float)hh);
  }
  __syncthreads();

  {
    const int rb = (16 * w + (lane & 15)) * 72 + (lane >> 4) * 8;
    const u32x4v ah0 = *(const u32x4v*)&Hsh[rb];
    const u32x4v ah1 = *(const u32x4v*)&Hsh[rb + 32];
    const u32x4v al0 = *(const u32x4v*)&Hsl[rb];
    const u32x4v al1 = *(const u32x4v*)&Hsl[rb + 32];
    u32x4v bh[4][2], bl[4][2];
#pragma unroll
    for (int gt = 0; gt < 4; ++gt)
#pragma unroll
      for (int ks = 0; ks < 2; ++ks) {
        bh[gt][ks] = *(const u32x4v*)&w1Fh[(gt * 2 + ks) * 64 + lane];
        bl[gt][ks] = *(const u32x4v*)&w1Fl[(gt * 2 + ks) * 64 + lane];
      }
    f32x4 qa[4] = {};
#pragma unroll
    for (int gt = 0; gt < 4; ++gt) MFMA_VV(qa[gt], ah0, bh[gt][0]);
#pragma unroll
    for (int gt = 0; gt < 4; ++gt) MFMA_VV(qa[gt], ah1, bh[gt][1]);
#pragma unroll
    for (int gt = 0; gt < 4; ++gt) MFMA_VV(qa[gt], al0, bh[gt][0]);
#pragma unroll
    for (int gt = 0; gt < 4; ++gt) MFMA_VV(qa[gt], al1, bh[gt][1]);
#pragma unroll
    for (int gt = 0; gt < 4; ++gt) MFMA_VV(qa[gt], ah0, bl[gt][0]);
#pragma unroll
    for (int gt = 0; gt < 4; ++gt) MFMA_VV(qa[gt], ah1, bl[gt][1]);
    asm volatile("s_nop 7\n\ts_nop 7");
#pragma unroll
    for (int gt = 0; gt < 4; ++gt) {
      const int g = 16 * gt + (lane & 15);
      float r0, r1, r2, r3;
      uint2 uh, ul;
      uh.x = pk2(qa[gt].x, qa[gt].y, r0, r1);
      uh.y = pk2(qa[gt].z, qa[gt].w, r2, r3);
      ul.x = pk2r(r0, r1);
      ul.y = pk2r(r2, r3);
      *(uint2*)&Qth[g * 72 + 16 * w + (lane >> 4) * 4] = uh;
      *(uint2*)&Qtl[g * 72 + 16 * w + (lane >> 4) * 4] = ul;
    }
  }
  __syncthreads();

  {
    u32x4v aah[2], aal[2];
#pragma unroll
    for (int ks = 0; ks < 2; ++ks) {
      aah[ks] = *(const u32x4v*)&adjFh[(w * 2 + ks) * 64 + lane];
      aal[ks] = *(const u32x4v*)&adjFl[(w * 2 + ks) * 64 + lane];
    }
    u32x4v qbh[4][2], qbl[4][2];
#pragma unroll
    for (int gt = 0; gt < 4; ++gt)
#pragma unroll
      for (int ks = 0; ks < 2; ++ks) {
        const int rb3 = (16 * gt + (lane & 15)) * 72 + ks * 32 + (lane >> 4) * 8;
        qbh[gt][ks] = *(const u32x4v*)&Qth[rb3];
        qbl[gt][ks] = *(const u32x4v*)&Qtl[rb3];
      }
    f32x4 oa[4] = {};
#pragma unroll
    for (int gt = 0; gt < 4; ++gt) MFMA_VV(oa[gt], aah[0], qbh[gt][0]);
#pragma unroll
    for (int gt = 0; gt < 4; ++gt) MFMA_VV(oa[gt], aah[1], qbh[gt][1]);
#pragma unroll
    for (int gt = 0; gt < 4; ++gt) MFMA_VV(oa[gt], aal[0], qbh[gt][0]);
#pragma unroll
    for (int gt = 0; gt < 4; ++gt) MFMA_VV(oa[gt], aal[1], qbh[gt][1]);
#pragma unroll
    for (int gt = 0; gt < 4; ++gt) MFMA_VV(oa[gt], aah[0], qbl[gt][0]);
#pragma unroll
    for (int gt = 0; gt < 4; ++gt) MFMA_VV(oa[gt], aah[1], qbl[gt][1]);
    asm volatile("s_nop 7\n\ts_nop 7");

    _Float16* oh = seqh + (size_t)blockIdx.x * 4096;
    _Float16* ol = seql + (size_t)blockIdx.x * 4096;
    const int ub = 16 * w + (lane >> 4) * 4;
#pragma unroll
    for (int gt = 0; gt < 4; ++gt) {
      const int g = 16 * gt + (lane & 15);
      const float bv = b1[g];
#pragma unroll
      for (int q = 0; q < 4; ++q) {
        const float val = fmaxf(oa[gt][q] + bv, 0.f);
        const _Float16 hv = (_Float16)val;
        oh[(ub + q) * 64 + g] = hv;
        ol[(ub + q) * 64 + g] = (_Float16)(val - (float)hv);
      }
    }
  }
}

// ----------------------------------------------- MFMA GEMM  C = A@B^T + bias
// R20/R21 version (gload_lds staging). Used for gemm0 (+ serial fallback).
__global__ __launch_bounds__(256, 2) void k_gemm_lds(
    const _Float16* __restrict__ Ah, const _Float16* __restrict__ Al,
    const _Float16* __restrict__ Bh, const _Float16* __restrict__ Bl,
    const float* __restrict__ bias,
    float* __restrict__ C,
    int K, int mBlocks)
{
  __shared__ u32x4v frag[2][32][64];
  const int bid = blockIdx.x;
  const int mb = bid % mBlocks;
  const int nb = bid / mBlocks;
  const int t = threadIdx.x;
  const int w = t >> 6, l = t & 63;
  const int m0 = mb * 128, n0 = nb * 128;
  const int mh = w >> 1, nh = w & 1;
  const int row = l & 15;

  const _Float16* src[8];
#pragma unroll
  for (int s = 0; s < 8; ++s) {
    const int gs = w * 8 + s;
    const bool isB = gs >= 16;
    const int tile = (gs & 15) >> 1;
    const int hl = gs & 1;
    const _Float16* base = isB ? (hl ? Bl : Bh) : (hl ? Al : Ah);
    const int r = (isB ? n0 : m0) + 16 * tile + row;
    src[s] = base + (size_t)r * K + ((l >> 4) * 8);
  }

  f32x4 acc[4][4] = {};

#pragma unroll
  for (int s = 0; s < 8; ++s)
    GLOAD_LDS16(src[s], &frag[0][w * 8 + s][0]);
  __syncthreads();

  int cur = 0;
#pragma unroll 1
  for (int kt = 0; kt < K; kt += 32) {
    const bool more = (kt + 32) < K;
    if (more) {
#pragma unroll
      for (int s = 0; s < 8; ++s)
        GLOAD_LDS16(src[s] + kt + 32, &frag[cur ^ 1][w * 8 + s][0]);
    }

    u32x4v afh[4], afl[4], bfh[4], bfl[4];
#pragma unroll
    for (int i = 0; i < 4; ++i) {
      afh[i] = frag[cur][2 * (mh * 4 + i)][l];
      afl[i] = frag[cur][2 * (mh * 4 + i) + 1][l];
      bfh[i] = frag[cur][16 + 2 * (nh * 4 + i)][l];
      bfl[i] = frag[cur][16 + 2 * (nh * 4 + i) + 1][l];
    }

#pragma unroll
    for (int mi = 0; mi < 4; ++mi)
#pragma unroll
      for (int ni = 0; ni < 4; ++ni)
        MFMA_VV(acc[mi][ni], afh[mi], bfh[ni]);
#pragma unroll
    for (int mi = 0; mi < 4; ++mi)
#pragma unroll
      for (int ni = 0; ni < 4; ++ni)
        MFMA_VV(acc[mi][ni], afl[mi], bfh[ni]);
#pragma unroll
    for (int mi = 0; mi < 4; ++mi)
#pragma unroll
      for (int ni = 0; ni < 4; ++ni)
        MFMA_VV(acc[mi][ni], afh[mi], bfl[ni]);

    __syncthreads();
    cur ^= 1;
  }

  asm volatile("s_nop 7\n\ts_nop 7");

  const int m0w = m0 + mh * 64;
  const int n0w = n0 + nh * 64;
  const int r4 = (l >> 4) * 4;
#pragma unroll
  for (int ni = 0; ni < 4; ++ni) {
    const float bv = bias[n0w + 16 * ni + row];
#pragma unroll
    for (int mi = 0; mi < 4; ++mi) {
      float* cp = C + (size_t)(m0w + 16 * mi + r4) * 768 + n0w + 16 * ni + row;
      cp[0]    = acc[mi][ni].x + bv;
      cp[768]  = acc[mi][ni].y + bv;
      cp[1536] = acc[mi][ni].z + bv;
      cp[2304] = acc[mi][ni].w + bv;
    }
  }
}

// ------------------------------------------------------------------ GRU layer
// R19/R21 serial version (fallback only).
template <bool WF16, bool LASTONLY>
__global__ __launch_bounds__(512, 2) void k_gru(
    const float* __restrict__ gi,
    const uint4* __restrict__ wp,
    const float* __restrict__ bhh,
    float* __restrict__ ys,
    _Float16* __restrict__ ysh,
    _Float16* __restrict__ ysl)
{
  const int b = blockIdx.x;
  const int t = threadIdx.x;
  const int w = t >> 6;
  const int l = t & 63;

  __shared__ __align__(16) _Float16 h2[2][256];

  const u32x4v* wp4 = (const u32x4v*)wp;
  const int wbase = w * 6;

#define LBK(nt, ks) const u32x4v b##nt##_##ks = wp4[(((wbase + nt) * 8 + ks) << 6) + l];
#define LBNT(nt) LBK(nt,0) LBK(nt,1) LBK(nt,2) LBK(nt,3) \
                 LBK(nt,4) LBK(nt,5) LBK(nt,6) LBK(nt,7)
  LBNT(0) LBNT(1) LBNT(2) LBNT(3) LBNT(4) LBNT(5)
#undef LBNT
#undef LBK

  const int half = (l >> 4) & 1;
  const int j = 16 * w + (l & 15) + 128 * half;
  const bool act = (l < 32);
  float br = 0.f, bz = 0.f, bn = 0.f;
  float hold = 0.f;
  if (act) { br = bhh[j]; bz = bhh[256 + j]; bn = bhh[512 + j]; }
  if (t < 256) { h2[0][t] = (_Float16)0.f; h2[1][t] = (_Float16)0.f; }
  __syncthreads();

  const float* gib = gi + (size_t)b * 512 * 768;
  const char* h2c = (const char*)h2;
  const int g16 = (l >> 4) * 16;
  int cur = 0;

#pragma unroll 1
  for (int step = 0; step < 512; ++step) {
    float ir = 0.f, iz = 0.f, inn = 0.f;
    if (act) {
      const float* g = gib + (size_t)step * 768;
      ir = g[j]; iz = g[256 + j]; inn = g[512 + j];
    }

    f32x4 c0 = {0.f,0.f,0.f,0.f}, c1 = c0, c2 = c0, c3 = c0, c4 = c0, c5 = c0;

#define DOT_KS(ks) { \
    const u32x4v a = *(const u32x4v*)(h2c + cur * 512 + (ks) * 64 + g16); \
    MFMA_A(c0, a, b0_##ks); MFMA_A(c1, a, b1_##ks); MFMA_A(c2, a, b2_##ks); \
    MFMA_A(c3, a, b3_##ks); MFMA_A(c4, a, b4_##ks); MFMA_A(c5, a, b5_##ks); }
    DOT_KS(0) DOT_KS(1) DOT_KS(2) DOT_KS(3)
    DOT_KS(4) DOT_KS(5) DOT_KS(6) DOT_KS(7)
#undef DOT_KS
    asm volatile("s_nop 7\n\ts_nop 7");

    if (act) {
      const float cr = half ? c1.x : c0.x;
      const float cz = half ? c3.x : c2.x;
      const float cn = half ? c5.x : c4.x;
      const float r = __builtin_amdgcn_rcpf(1.f + __expf(-(ir + cr + br)));
      const float z = __builtin_amdgcn_rcpf(1.f + __expf(-(iz + cz + bz)));
      const float e2 = __expf(2.f * (inn + r * (cn + bn)));
      const float n = 1.f - 2.f * __builtin_amdgcn_rcpf(e2 + 1.f);
      hold = (1.f - z) * n + z * hold;
      h2[cur ^ 1][j] = (_Float16)hold;
      const size_t rowi = (size_t)b * 512 + step;
      if (WF16) {
        const _Float16 hh = (_Float16)hold;
        ysh[rowi * 256 + j] = hh;
        ysl[rowi * 256 + j] = (_Float16)(hold - (float)hh);
      }
      if (LASTONLY) {
        if (step == 511) ys[rowi * 256 + j] = hold;
      }
    }
    GRU_BARRIER();
    cur ^= 1;
  }
}

// ----------------------------------------- fused pipelined GRU0+gemm1+GRU1
// blocks 0-31: GRU0(batch bid) -> ysh/ysl + progress publish every 16 steps.
// blocks 32-63: GRU1(batch bid-32): per 128-step group: acquire-wait, inline
// gemm tile (ys@Wih1^T + bih1 -> gi1), barrier, 128 recurrence steps.
__global__ __launch_bounds__(512, 2) void k_gru_fused(
    const float* __restrict__ gi0,
    float* __restrict__ gi1,
    const uint4* __restrict__ wp0, const uint4* __restrict__ wp1,
    const float* __restrict__ bhh0, const float* __restrict__ bhh1,
    const _Float16* __restrict__ bh1, const _Float16* __restrict__ bl1,
    const float* __restrict__ bih1,
    float* __restrict__ ys1,
    _Float16* __restrict__ ysh, _Float16* __restrict__ ysl,
    int* __restrict__ prog)
{
  const int bid = blockIdx.x;
  const bool role0 = bid < 32;
  const int b = role0 ? bid : bid - 32;
  const int t = threadIdx.x;
  const int w = t >> 6;
  const int l = t & 63;

  __shared__ __align__(16) _Float16 h2[2][256];

  const u32x4v* wp4 = (const u32x4v*)(role0 ? wp0 : wp1);
  const float* bhh = role0 ? bhh0 : bhh1;
  const int wbase = w * 6;

#define LBK(nt, ks) const u32x4v b##nt##_##ks = wp4[(((wbase + nt) * 8 + ks) << 6) + l];
#define LBNT(nt) LBK(nt,0) LBK(nt,1) LBK(nt,2) LBK(nt,3) \
                 LBK(nt,4) LBK(nt,5) LBK(nt,6) LBK(nt,7)
  LBNT(0) LBNT(1) LBNT(2) LBNT(3) LBNT(4) LBNT(5)
#undef LBNT
#undef LBK

  const int half = (l >> 4) & 1;
  const int j = 16 * w + (l & 15) + 128 * half;
  const bool act = (l < 32);
  float br = 0.f, bz = 0.f, bn = 0.f;
  float hold = 0.f;
  if (act) { br = bhh[j]; bz = bhh[256 + j]; bn = bhh[512 + j]; }
  if (t < 256) { h2[0][t] = (_Float16)0.f; h2[1][t] = (_Float16)0.f; }
  __syncthreads();

  const char* h2c = (const char*)h2;
  const int g16 = (l >> 4) * 16;
  int cur = 0;

#define STEP_BODY(gibase, step, DO_WF16, DO_LAST) { \
    float ir = 0.f, iz = 0.f, inn = 0.f; \
    if (act) { \
      const float* g = (gibase) + (size_t)(step) * 768; \
      ir = g[j]; iz = g[256 + j]; inn = g[512 + j]; \
    } \
    f32x4 c0 = {0.f,0.f,0.f,0.f}, c1 = c0, c2 = c0, c3 = c0, c4 = c0, c5 = c0; \
    { const u32x4v a = *(const u32x4v*)(h2c + cur * 512 + 0 * 64 + g16); \
      MFMA_A(c0, a, b0_0); MFMA_A(c1, a, b1_0); MFMA_A(c2, a, b2_0); \
      MFMA_A(c3, a, b3_0); MFMA_A(c4, a, b4_0); MFMA_A(c5, a, b5_0); } \
    { const u32x4v a = *(const u32x4v*)(h2c + cur * 512 + 1 * 64 + g16); \
      MFMA_A(c0, a, b0_1); MFMA_A(c1, a, b1_1); MFMA_A(c2, a, b2_1); \
      MFMA_A(c3, a, b3_1); MFMA_A(c4, a, b4_1); MFMA_A(c5, a, b5_1); } \
    { const u32x4v a = *(const u32x4v*)(h2c + cur * 512 + 2 * 64 + g16); \
      MFMA_A(c0, a, b0_2); MFMA_A(c1, a, b1_2); MFMA_A(c2, a, b2_2); \
      MFMA_A(c3, a, b3_2); MFMA_A(c4, a, b4_2); MFMA_A(c5, a, b5_2); } \
    { const u32x4v a = *(const u32x4v*)(h2c + cur * 512 + 3 * 64 + g16); \
      MFMA_A(c0, a, b0_3); MFMA_A(c1, a, b1_3); MFMA_A(c2, a, b2_3); \
      MFMA_A(c3, a, b3_3); MFMA_A(c4, a, b4_3); MFMA_A(c5, a, b5_3); } \
    { const u32x4v a = *(const u32x4v*)(h2c + cur * 512 + 4 * 64 + g16); \
      MFMA_A(c0, a, b0_4); MFMA_A(c1, a, b1_4); MFMA_A(c2, a, b2_4); \
      MFMA_A(c3, a, b3_4); MFMA_A(c4, a, b4_4); MFMA_A(c5, a, b5_4); } \
    { const u32x4v a = *(const u32x4v*)(h2c + cur * 512 + 5 * 64 + g16); \
      MFMA_A(c0, a, b0_5); MFMA_A(c1, a, b1_5); MFMA_A(c2, a, b2_5); \
      MFMA_A(c3, a, b3_5); MFMA_A(c4, a, b4_5); MFMA_A(c5, a, b5_5); } \
    { const u32x4v a = *(const u32x4v*)(h2c + cur * 512 + 6 * 64 + g16); \
      MFMA_A(c0, a, b0_6); MFMA_A(c1, a, b1_6); MFMA_A(c2, a, b2_6); \
      MFMA_A(c3, a, b3_6); MFMA_A(c4, a, b4_6); MFMA_A(c5, a, b5_6); } \
    { const u32x4v a = *(const u32x4v*)(h2c + cur * 512 + 7 * 64 + g16); \
      MFMA_A(c0, a, b0_7); MFMA_A(c1, a, b1_7); MFMA_A(c2, a, b2_7); \
      MFMA_A(c3, a, b3_7); MFMA_A(c4, a, b4_7); MFMA_A(c5, a, b5_7); } \
    asm volatile("s_nop 7\n\ts_nop 7"); \
    if (act) { \
      const float cr = half ? c1.x : c0.x; \
      const float cz = half ? c3.x : c2.x; \
      const float cn = half ? c5.x : c4.x; \
      const float r = __builtin_amdgcn_rcpf(1.f + __expf(-(ir + cr + br))); \
      const float z = __builtin_amdgcn_rcpf(1.f + __expf(-(iz + cz + bz))); \
      const float e2 = __expf(2.f * (inn + r * (cn + bn))); \
      const float n = 1.f - 2.f * __builtin_amdgcn_rcpf(e2 + 1.f); \
      hold = (1.f - z) * n + z * hold; \
      h2[cur ^ 1][j] = (_Float16)hold; \
      const size_t rowi = (size_t)b * 512 + (step); \
      if (DO_WF16) { \
        const _Float16 hh = (_Float16)hold; \
        ysh[rowi * 256 + j] = hh; \
        ysl[rowi * 256 + j] = (_Float16)(hold - (float)hh); \
      } \
      if (DO_LAST) { if ((step) == 511) ys1[rowi * 256 + j] = hold; } \
    } \
  }

  if (role0) {
    const float* gib = gi0 + (size_t)b * 512 * 768;
#pragma unroll 1
    for (int step = 0; step < 512; ++step) {
      STEP_BODY(gib, step, true, false)
      if ((step & 15) == 15) {
        __syncthreads();   // full drain: ysh/ysl stores of steps <= step in L2
        if (t == 0)
          __hip_atomic_store(&prog[b], step + 1, __ATOMIC_RELEASE,
                             __HIP_MEMORY_SCOPE_AGENT);
      } else {
        GRU_BARRIER();
      }
      cur ^= 1;
    }
  } else {
    float* gi1b = gi1 + (size_t)b * 512 * 768;
#pragma unroll 1
    for (int g = 0; g < 4; ++g) {
      if (t == 0) {
        while (__hip_atomic_load(&prog[b], __ATOMIC_ACQUIRE,
                                 __HIP_MEMORY_SCOPE_AGENT) < 128 * (g + 1))
          __builtin_amdgcn_s_sleep(8);
      }
      __syncthreads();
      // ---- inline gemm: rows b*512+128g .. +127, gi1 = ys@Wih1^T + bih1
      {
        const size_t arow =
            ((size_t)b * 512 + 128 * g + 16 * w + (l & 15)) * 256 + (l >> 4) * 8;
        const size_t orowb = (size_t)128 * g + 16 * w + 4 * (l >> 4);
#pragma unroll 1
        for (int ct = 0; ct < 48; ++ct) {
          const int col = 16 * ct + (l & 15);
          const size_t brow = (size_t)col * 256 + (l >> 4) * 8;
          f32x4 acc = {0.f, 0.f, 0.f, 0.f};
#pragma unroll
          for (int ks = 0; ks < 8; ++ks) {
            const u32x4v a_h = *(const u32x4v*)(ysh + arow + 32 * ks);
            const u32x4v a_l = *(const u32x4v*)(ysl + arow + 32 * ks);
            const u32x4v bfh = *(const u32x4v*)(bh1 + brow + 32 * ks);
            const u32x4v bfl = *(const u32x4v*)(bl1 + brow + 32 * ks);
            MFMA_VV(acc, a_h, bfh);
            MFMA_VV(acc, a_l, bfh);
            MFMA_VV(acc, a_h, bfl);
          }
          asm volatile("s_nop 7\n\ts_nop 7");
          const float bv = bih1[col];
#pragma unroll
          for (int q = 0; q < 4; ++q)
            gi1b[(orowb + q) * 768 + col] = acc[q] + bv;
        }
      }
      __syncthreads();   // drain gi1 writes before recurrence reads
      // ---- 128 recurrence steps
#pragma unroll 1
      for (int s2 = 0; s2 < 128; ++s2) {
        const int step = 128 * g + s2;
        STEP_BODY(gi1b, step, false, true)
        GRU_BARRIER();
        cur ^= 1;
      }
    }
  }
#undef STEP_BODY
}

// ------------------------------------------------------------------ FC head
__global__ __launch_bounds__(128) void k_head(
    const float* __restrict__ ys1,
    const float* __restrict__ fc1w, const float* __restrict__ fc1b,
    const float* __restrict__ fc2w, const float* __restrict__ fc2b,
    float* __restrict__ out)
{
  __shared__ float last[256];
  __shared__ float o1[128];
  const int b = blockIdx.x, t = threadIdx.x;
  const float* src = ys1 + (size_t)(b * 512 + 511) * 256;
  last[t] = src[t];
  last[128 + t] = src[128 + t];
  __syncthreads();
  float acc = fc1b[t];
#pragma unroll 8
  for (int k = 0; k < 256; ++k) acc += last[k] * fc1w[k * 128 + t];
  o1[t] = fmaxf(acc, 0.f);
  __syncthreads();
  if (t < 64) {
    float acc2 = fc2b[t];
#pragma unroll 8
    for (int i = 0; i < 128; ++i) acc2 += o1[i] * fc2w[i * 64 + t];
    out[b * 64 + t] = acc2;
  }
}

// ------------------------------------------------------------------ launcher
extern "C" void kernel_launch(void* const* d_in, const int* in_sizes, int n_in,
                              void* d_out, int out_size, void* d_ws, size_t ws_size,
                              hipStream_t stream)
{
  const float* x    = (const float*)d_in[0];
  const float* adj  = (const float*)d_in[1];
  const float* W0   = (const float*)d_in[2];
  const float* b0   = (const float*)d_in[3];
  const float* W1   = (const float*)d_in[4];
  const float* b1   = (const float*)d_in[5];
  const float* bng  = (const float*)d_in[6];
  const float* bnbb = (const float*)d_in[7];
  const float* bnm  = (const float*)d_in[8];
  const float* bnv  = (const float*)d_in[9];
  const float* Wih0 = (const float*)d_in[10];
  const float* Whh0 = (const float*)d_in[11];
  const float* bih0 = (const float*)d_in[12];
  const float* bhh0 = (const float*)d_in[13];
  const float* Wih1 = (const float*)d_in[14];
  const float* Whh1 = (const float*)d_in[15];
  const float* bih1 = (const float*)d_in[16];
  const float* bhh1 = (const float*)d_in[17];
  const float* fc1w = (const float*)d_in[18];
  const float* fc1b = (const float*)d_in[19];
  const float* fc2w = (const float*)d_in[20];
  const float* fc2b = (const float*)d_in[21];
  float* out = (float*)d_out;

  float* ws = (float*)d_ws;
  const size_t fixed = (size_t)16384 * 768 + (size_t)16384 * 256
                     + 2 * ((size_t)16384 * 128)
                     + 2 * 98304
                     + 2 * ((size_t)768 * 4096 / 2)
                     + 2 * ((size_t)768 * 256 / 2)
                     + 4 * 2048 + 64;
  int CHUNK = 16384;
  while (CHUNK > 128 && ((size_t)CHUNK * 4096 + fixed) * 4 > ws_size) CHUNK >>= 1;

  size_t off = 0;
  _Float16* seqh = (_Float16*)(ws + off); off += (size_t)CHUNK * 2048;
  _Float16* seql = (_Float16*)(ws + off); off += (size_t)CHUNK * 2048;
  float* gi      = ws + off; off += (size_t)16384 * 768;
  float* ys1     = ws + off; off += (size_t)16384 * 256;
  _Float16* ysh  = (_Float16*)(ws + off); off += (size_t)16384 * 128;
  _Float16* ysl  = (_Float16*)(ws + off); off += (size_t)16384 * 128;
  uint4* wp0     = (uint4*)(ws + off); off += 98304;
  uint4* wp1     = (uint4*)(ws + off); off += 98304;
  _Float16* bh0  = (_Float16*)(ws + off); off += (size_t)768 * 2048;
  _Float16* bl0  = (_Float16*)(ws + off); off += (size_t)768 * 2048;
  _Float16* bh1  = (_Float16*)(ws + off); off += (size_t)768 * 128;
  _Float16* bl1  = (_Float16*)(ws + off); off += (size_t)768 * 128;
  uint4* adjFh   = (uint4*)(ws + off); off += 2048;
  uint4* adjFl   = (uint4*)(ws + off); off += 2048;
  uint4* w1Fh    = (uint4*)(ws + off); off += 2048;
  uint4* w1Fl    = (uint4*)(ws + off); off += 2048;
  int*   prog    = (int*)(ws + off);  off += 64;
  // gi1 aliased onto the dead seq region (seqh+seql = CHUNK*4096 floats)
  float* gi1     = (float*)seqh;

  k_pack_frag<<<96, 256, 0, stream>>>(Whh0, wp0);
  k_pack_frag<<<96, 256, 0, stream>>>(Whh1, wp1);
  k_pack_gcn<<<4, 256, 0, stream>>>(adj, W1, adjFh, adjFl, w1Fh, w1Fl);
  k_split16<<<(3145728 + 255) / 256, 256, 0, stream>>>(Wih0, bh0, bl0, 3145728);
  k_split16<<<(196608 + 255) / 256, 256, 0, stream>>>(Wih1, bh1, bl1, 196608);

  const int nChunks = 16384 / CHUNK;
  for (int ci = 0; ci < nChunks; ++ci) {
    const int base = ci * CHUNK;
    k_gcn<<<CHUNK, 256, 0, stream>>>(x, adj, W0, b0, adjFh, adjFl, w1Fh, w1Fl,
                                     b1, bng, bnbb, bnm, bnv, seqh, seql, base);
    const int mB = CHUNK / 128;
    k_gemm_lds<<<mB * 6, 256, 0, stream>>>(seqh, seql, bh0, bl0, bih0,
                                           gi + (size_t)base * 768, 4096, mB);
  }

  if (CHUNK >= 4096) {
    // pipelined path: GRU0 + inline gemm1 + GRU1 in one 64-block kernel
    hipMemsetAsync(prog, 0, 32 * sizeof(int), stream);
    k_gru_fused<<<64, 512, 0, stream>>>(gi, gi1, wp0, wp1, bhh0, bhh1,
                                        bh1, bl1, bih1, ys1, ysh, ysl, prog);
  } else {
    // serial fallback (tiny-ws case)
    k_gru<true, false><<<32, 512, 0, stream>>>(gi, wp0, bhh0, nullptr, ysh, ysl);
    k_gemm_lds<<<128 * 6, 256, 0, stream>>>(ysh, ysl, bh1, bl1, bih1, gi, 256, 128);
    k_gru<false, true><<<32, 512, 0, stream>>>(gi, wp1, bhh1, ys1, nullptr, nullptr);
  }
  k_head<<<32, 128, 0, stream>>>(ys1, fc1w, fc1b, fc2w, fc2b, out);
}

// Round 23
// 2148.392 us; speedup vs baseline: 1.4499x; 1.4499x over previous
//
#include <hip/hip_runtime.h>
#include <hip/hip_bf16.h>

// TSGCN: GCN(2 layers, fused) -> GRU(4096->256) -> GRU(256->256) -> FC head
// B=32 S=512 N=64 F=16 G=64 H=256.
// R23 = R21 EXACT (best proven config: 2152us, absmax 7.324e-4).
// R22's fused GRU0/gemm/GRU1 pipeline REVERTED: it pushed VGPR 124->128
// (third confirmation that crossing that boundary wrecks the GRU MFMA
// schedule: MfmaUtil 6.0->3.9) and the producer-side vmcnt(0) drains +
// consumer interference tripled FETCH_SIZE. Serial chain is optimal here.
// Frozen: GRU inner loop (R12/R15/R19 DOT_KS form), gload_lds gemm, MFMA GCN.

#define EPS_BN 1e-5f

typedef float f32x4 __attribute__((ext_vector_type(4)));
typedef unsigned u32x4v __attribute__((ext_vector_type(4)));

// LDS-only barrier: global stores/loads in flight are NOT drained
#define GRU_BARRIER() do {                       \
    asm volatile("" ::: "memory");               \
    asm volatile("s_waitcnt lgkmcnt(0)");        \
    __builtin_amdgcn_s_barrier();                \
    asm volatile("" ::: "memory");               \
  } while (0)

#define MFMA_VV(c, a, b) asm volatile("v_mfma_f32_16x16x32_f16 %0, %1, %2, %0" \
                                      : "+v"(c) : "v"(a), "v"(b))
#define MFMA_A(c, a, b) asm volatile("v_mfma_f32_16x16x32_f16 %0, %1, %2, %0" \
                                     : "+v"(c) : "v"(a), "a"(b))

// async global->LDS, 16B per lane: dest = wave-uniform base + lane*16
#define GLOAD_LDS16(gp, lp) \
  __builtin_amdgcn_global_load_lds( \
      (const __attribute__((address_space(1))) void*)(gp), \
      (__attribute__((address_space(3))) void*)(lp), 16, 0, 0)

// ---------------------------------------------------- fp32 -> f16 hi/lo split
__global__ void k_split16(const float* __restrict__ src,
                          _Float16* __restrict__ hi, _Float16* __restrict__ lo,
                          int n) {
  int i = blockIdx.x * 256 + threadIdx.x;
  if (i >= n) return;
  float v = src[i];
  _Float16 h = (_Float16)v;
  hi[i] = h;
  lo[i] = (_Float16)(v - (float)h);
}

// ---------------------------------------------- pack Whh into MFMA B-fragments
__global__ void k_pack_frag(const float* __restrict__ whh, uint4* __restrict__ wp) {
  int tid = blockIdx.x * 256 + threadIdx.x;
  if (tid >= 24576) return;
  int l = tid & 63;
  int rest = tid >> 6;
  int ks = rest & 7; rest >>= 3;
  int nt = rest % 6;
  int w  = rest / 6;
  int n  = 16 * w + 128 * nt + (l & 15);
  int kb = ks * 32 + (l >> 4) * 8;
  const float* src = whh + (size_t)n * 256 + kb;
  unsigned dw[4];
#pragma unroll
  for (int d = 0; d < 4; ++d) {
    unsigned short lo = __builtin_bit_cast(unsigned short, (_Float16)src[2 * d]);
    unsigned short hi = __builtin_bit_cast(unsigned short, (_Float16)src[2 * d + 1]);
    dw[d] = (unsigned)lo | ((unsigned)hi << 16);
  }
  wp[tid] = make_uint4(dw[0], dw[1], dw[2], dw[3]);
}

// ------------------------------------- pack adj (A-frags) + W1 (B-frags) hi/lo
__global__ void k_pack_gcn(const float* __restrict__ adj, const float* __restrict__ W1,
                           uint4* __restrict__ adjFh, uint4* __restrict__ adjFl,
                           uint4* __restrict__ w1Fh, uint4* __restrict__ w1Fl) {
  int tid = blockIdx.x * 256 + threadIdx.x;
  if (tid >= 1024) return;
  int l = tid & 63;
  int fi = (tid >> 6) & 7;
  bool isW1 = tid >= 512;
  int tile = fi >> 1, ks = fi & 1;
  int rc = tile * 16 + (l & 15);
  int kb = ks * 32 + (l >> 4) * 8;
  unsigned hdw[4], ldw[4];
#pragma unroll
  for (int d2 = 0; d2 < 4; ++d2) {
    unsigned short hv2[2], lv2[2];
#pragma unroll
    for (int e = 0; e < 2; ++e) {
      int k = kb + 2 * d2 + e;
      float v = isW1 ? W1[k * 64 + rc] : adj[rc * 64 + k];
      _Float16 hv = (_Float16)v;
      _Float16 lv = (_Float16)(v - (float)hv);
      hv2[e] = __builtin_bit_cast(unsigned short, hv);
      lv2[e] = __builtin_bit_cast(unsigned short, lv);
    }
    hdw[d2] = (unsigned)hv2[0] | ((unsigned)hv2[1] << 16);
    ldw[d2] = (unsigned)lv2[0] | ((unsigned)lv2[1] << 16);
  }
  uint4 hq = make_uint4(hdw[0], hdw[1], hdw[2], hdw[3]);
  uint4 lq = make_uint4(ldw[0], ldw[1], ldw[2], ldw[3]);
  if (isW1) { w1Fh[fi * 64 + l] = hq; w1Fl[fi * 64 + l] = lq; }
  else      { adjFh[fi * 64 + l] = hq; adjFl[fi * 64 + l] = lq; }
}

// f16 hi pack of two floats; residuals returned
static __device__ __forceinline__ unsigned pk2(float a, float b, float& ra, float& rb) {
  _Float16 ha = (_Float16)a, hb = (_Float16)b;
  ra = a - (float)ha; rb = b - (float)hb;
  return (unsigned)__builtin_bit_cast(unsigned short, ha) |
         ((unsigned)__builtin_bit_cast(unsigned short, hb) << 16);
}
static __device__ __forceinline__ unsigned pk2r(float a, float b) {
  _Float16 ha = (_Float16)a, hb = (_Float16)b;
  return (unsigned)__builtin_bit_cast(unsigned short, ha) |
         ((unsigned)__builtin_bit_cast(unsigned short, hb) << 16);
}

// ------------------------------------------------------------- fused GCN
// (R19 proven version, unchanged)
__global__ __launch_bounds__(256) void k_gcn(
    const float* __restrict__ x,
    const float* __restrict__ adj,
    const float* __restrict__ W0, const float* __restrict__ b0,
    const uint4* __restrict__ adjFh, const uint4* __restrict__ adjFl,
    const uint4* __restrict__ w1Fh, const uint4* __restrict__ w1Fl,
    const float* __restrict__ b1,
    const float* __restrict__ bn_g, const float* __restrict__ bn_b,
    const float* __restrict__ bn_m, const float* __restrict__ bn_v,
    _Float16* __restrict__ seqh, _Float16* __restrict__ seql, int base)
{
  __shared__ float AsT[4096];
  __shared__ float Xs[1024];
  __shared__ __align__(16) _Float16 Hsh[64 * 72], Hsl[64 * 72];
  __shared__ __align__(16) _Float16 Qth[64 * 72], Qtl[64 * 72];
  __shared__ float bnm_s[64], bns_s[64], bnb_s[64];

  const int t = threadIdx.x;
  const int lane = t & 63;
  const int w = t >> 6;
  const int m = base + blockIdx.x;

  {
    const float4* a4 = (const float4*)adj;
#pragma unroll
    for (int p = 0; p < 4; ++p) {
      const int idx = t + 256 * p;
      const float4 av = a4[idx];
      const int u = idx >> 4, v4 = (idx & 15) * 4;
      AsT[(v4 + 0) * 64 + u] = av.x;
      AsT[(v4 + 1) * 64 + u] = av.y;
      AsT[(v4 + 2) * 64 + u] = av.z;
      AsT[(v4 + 3) * 64 + u] = av.w;
    }
    ((float4*)Xs)[t] = ((const float4*)(x + (size_t)m * 1024))[t];
  }
  if (t < 64) {
    bns_s[t] = rsqrtf(bn_v[t] + EPS_BN) * bn_g[t];
    bnm_s[t] = bn_m[t];
    bnb_s[t] = bn_b[t];
  }
  float w0r[16];
#pragma unroll
  for (int f = 0; f < 16; ++f) w0r[f] = W0[f * 64 + lane];
  const float b0v = b0[lane];
  __syncthreads();

  float axr[4] = {0.f, 0.f, 0.f, 0.f};
  const int f0 = w * 4;
#pragma unroll
  for (int v = 0; v < 64; ++v) {
    const float a_vu = AsT[v * 64 + lane];
    const float4 xv = *(const float4*)&Xs[v * 16 + f0];
    axr[0] = fmaf(a_vu, xv.x, axr[0]);
    axr[1] = fmaf(a_vu, xv.y, axr[1]);
    axr[2] = fmaf(a_vu, xv.z, axr[2]);
    axr[3] = fmaf(a_vu, xv.w, axr[3]);
  }
  __syncthreads();
#pragma unroll
  for (int j = 0; j < 4; ++j) Xs[lane * 16 + f0 + j] = axr[j];
  __syncthreads();

#pragma unroll
  for (int uu = 0; uu < 16; ++uu) {
    const int u = w * 16 + uu;
    float acc = 0.f;
#pragma unroll
    for (int f = 0; f < 16; ++f) acc += Xs[u * 16 + f] * w0r[f];
    float h1 = fmaxf(acc + b0v, 0.f);
    h1 = (h1 - bnm_s[u]) * bns_s[u] + bnb_s[u];
    const _Float16 hh = (_Float16)h1;
    Hsh[u * 72 + lane] = hh;
    Hsl[u * 72 + lane] = (_Float16)(h1 - (float)hh);
  }
  __syncthreads();

  // ---- stage 2 (MFMA): Q = H1@W1
  {
    const int rb = (16 * w + (lane & 15)) * 72 + (lane >> 4) * 8;
    const u32x4v ah0 = *(const u32x4v*)&Hsh[rb];
    const u32x4v ah1 = *(const u32x4v*)&Hsh[rb + 32];
    const u32x4v al0 = *(const u32x4v*)&Hsl[rb];
    const u32x4v al1 = *(const u32x4v*)&Hsl[rb + 32];
    u32x4v bh[4][2], bl[4][2];
#pragma unroll
    for (int gt = 0; gt < 4; ++gt)
#pragma unroll
      for (int ks = 0; ks < 2; ++ks) {
        bh[gt][ks] = *(const u32x4v*)&w1Fh[(gt * 2 + ks) * 64 + lane];
        bl[gt][ks] = *(const u32x4v*)&w1Fl[(gt * 2 + ks) * 64 + lane];
      }
    f32x4 qa[4] = {};
#pragma unroll
    for (int gt = 0; gt < 4; ++gt) MFMA_VV(qa[gt], ah0, bh[gt][0]);
#pragma unroll
    for (int gt = 0; gt < 4; ++gt) MFMA_VV(qa[gt], ah1, bh[gt][1]);
#pragma unroll
    for (int gt = 0; gt < 4; ++gt) MFMA_VV(qa[gt], al0, bh[gt][0]);
#pragma unroll
    for (int gt = 0; gt < 4; ++gt) MFMA_VV(qa[gt], al1, bh[gt][1]);
#pragma unroll
    for (int gt = 0; gt < 4; ++gt) MFMA_VV(qa[gt], ah0, bl[gt][0]);
#pragma unroll
    for (int gt = 0; gt < 4; ++gt) MFMA_VV(qa[gt], ah1, bl[gt][1]);
    asm volatile("s_nop 7\n\ts_nop 7");
#pragma unroll
    for (int gt = 0; gt < 4; ++gt) {
      const int g = 16 * gt + (lane & 15);
      float r0, r1, r2, r3;
      uint2 uh, ul;
      uh.x = pk2(qa[gt].x, qa[gt].y, r0, r1);
      uh.y = pk2(qa[gt].z, qa[gt].w, r2, r3);
      ul.x = pk2r(r0, r1);
      ul.y = pk2r(r2, r3);
      *(uint2*)&Qth[g * 72 + 16 * w + (lane >> 4) * 4] = uh;
      *(uint2*)&Qtl[g * 72 + 16 * w + (lane >> 4) * 4] = ul;
    }
  }
  __syncthreads();

  // ---- stage 3 (MFMA): OUT = relu(A@Q + b1)
  {
    u32x4v aah[2], aal[2];
#pragma unroll
    for (int ks = 0; ks < 2; ++ks) {
      aah[ks] = *(const u32x4v*)&adjFh[(w * 2 + ks) * 64 + lane];
      aal[ks] = *(const u32x4v*)&adjFl[(w * 2 + ks) * 64 + lane];
    }
    u32x4v qbh[4][2], qbl[4][2];
#pragma unroll
    for (int gt = 0; gt < 4; ++gt)
#pragma unroll
      for (int ks = 0; ks < 2; ++ks) {
        const int rb3 = (16 * gt + (lane & 15)) * 72 + ks * 32 + (lane >> 4) * 8;
        qbh[gt][ks] = *(const u32x4v*)&Qth[rb3];
        qbl[gt][ks] = *(const u32x4v*)&Qtl[rb3];
      }
    f32x4 oa[4] = {};
#pragma unroll
    for (int gt = 0; gt < 4; ++gt) MFMA_VV(oa[gt], aah[0], qbh[gt][0]);
#pragma unroll
    for (int gt = 0; gt < 4; ++gt) MFMA_VV(oa[gt], aah[1], qbh[gt][1]);
#pragma unroll
    for (int gt = 0; gt < 4; ++gt) MFMA_VV(oa[gt], aal[0], qbh[gt][0]);
#pragma unroll
    for (int gt = 0; gt < 4; ++gt) MFMA_VV(oa[gt], aal[1], qbh[gt][1]);
#pragma unroll
    for (int gt = 0; gt < 4; ++gt) MFMA_VV(oa[gt], aah[0], qbl[gt][0]);
#pragma unroll
    for (int gt = 0; gt < 4; ++gt) MFMA_VV(oa[gt], aah[1], qbl[gt][1]);
    asm volatile("s_nop 7\n\ts_nop 7");

    _Float16* oh = seqh + (size_t)blockIdx.x * 4096;
    _Float16* ol = seql + (size_t)blockIdx.x * 4096;
    const int ub = 16 * w + (lane >> 4) * 4;
#pragma unroll
    for (int gt = 0; gt < 4; ++gt) {
      const int g = 16 * gt + (lane & 15);
      const float bv = b1[g];
#pragma unroll
      for (int q = 0; q < 4; ++q) {
        const float val = fmaxf(oa[gt][q] + bv, 0.f);
        const _Float16 hv = (_Float16)val;
        oh[(ub + q) * 64 + g] = hv;
        ol[(ub + q) * 64 + g] = (_Float16)(val - (float)hv);
      }
    }
  }
}

// ----------------------------------------------- MFMA GEMM  C = A@B^T + bias
// R20/R21 version (kept): staging via global_load_lds.
__global__ __launch_bounds__(256, 2) void k_gemm_lds(
    const _Float16* __restrict__ Ah, const _Float16* __restrict__ Al,
    const _Float16* __restrict__ Bh, const _Float16* __restrict__ Bl,
    const float* __restrict__ bias,
    float* __restrict__ C,
    int K, int mBlocks)
{
  __shared__ u32x4v frag[2][32][64];
  const int bid = blockIdx.x;
  const int mb = bid % mBlocks;
  const int nb = bid / mBlocks;
  const int t = threadIdx.x;
  const int w = t >> 6, l = t & 63;
  const int m0 = mb * 128, n0 = nb * 128;
  const int mh = w >> 1, nh = w & 1;
  const int row = l & 15;

  const _Float16* src[8];
#pragma unroll
  for (int s = 0; s < 8; ++s) {
    const int gs = w * 8 + s;
    const bool isB = gs >= 16;
    const int tile = (gs & 15) >> 1;
    const int hl = gs & 1;
    const _Float16* base = isB ? (hl ? Bl : Bh) : (hl ? Al : Ah);
    const int r = (isB ? n0 : m0) + 16 * tile + row;
    src[s] = base + (size_t)r * K + ((l >> 4) * 8);
  }

  f32x4 acc[4][4] = {};

#pragma unroll
  for (int s = 0; s < 8; ++s)
    GLOAD_LDS16(src[s], &frag[0][w * 8 + s][0]);
  __syncthreads();

  int cur = 0;
#pragma unroll 1
  for (int kt = 0; kt < K; kt += 32) {
    const bool more = (kt + 32) < K;
    if (more) {
#pragma unroll
      for (int s = 0; s < 8; ++s)
        GLOAD_LDS16(src[s] + kt + 32, &frag[cur ^ 1][w * 8 + s][0]);
    }

    u32x4v afh[4], afl[4], bfh[4], bfl[4];
#pragma unroll
    for (int i = 0; i < 4; ++i) {
      afh[i] = frag[cur][2 * (mh * 4 + i)][l];
      afl[i] = frag[cur][2 * (mh * 4 + i) + 1][l];
      bfh[i] = frag[cur][16 + 2 * (nh * 4 + i)][l];
      bfl[i] = frag[cur][16 + 2 * (nh * 4 + i) + 1][l];
    }

#pragma unroll
    for (int mi = 0; mi < 4; ++mi)
#pragma unroll
      for (int ni = 0; ni < 4; ++ni)
        MFMA_VV(acc[mi][ni], afh[mi], bfh[ni]);
#pragma unroll
    for (int mi = 0; mi < 4; ++mi)
#pragma unroll
      for (int ni = 0; ni < 4; ++ni)
        MFMA_VV(acc[mi][ni], afl[mi], bfh[ni]);
#pragma unroll
    for (int mi = 0; mi < 4; ++mi)
#pragma unroll
      for (int ni = 0; ni < 4; ++ni)
        MFMA_VV(acc[mi][ni], afh[mi], bfl[ni]);

    __syncthreads();   // drains vmcnt: next buffer's gload_lds complete
    cur ^= 1;
  }

  asm volatile("s_nop 7\n\ts_nop 7");

  const int m0w = m0 + mh * 64;
  const int n0w = n0 + nh * 64;
  const int r4 = (l >> 4) * 4;
#pragma unroll
  for (int ni = 0; ni < 4; ++ni) {
    const float bv = bias[n0w + 16 * ni + row];
#pragma unroll
    for (int mi = 0; mi < 4; ++mi) {
      float* cp = C + (size_t)(m0w + 16 * mi + r4) * 768 + n0w + 16 * ni + row;
      cp[0]    = acc[mi][ni].x + bv;
      cp[768]  = acc[mi][ni].y + bv;
      cp[1536] = acc[mi][ni].z + bv;
      cp[2304] = acc[mi][ni].w + bv;
    }
  }
}

// ------------------------------------------------------------------ GRU layer
// R19 version EXACT (proven 673us / 124 VGPR). FROZEN.
template <bool WF16, bool LASTONLY>
__global__ __launch_bounds__(512, 2) void k_gru(
    const float* __restrict__ gi,
    const uint4* __restrict__ wp,
    const float* __restrict__ bhh,
    float* __restrict__ ys,
    _Float16* __restrict__ ysh,
    _Float16* __restrict__ ysl)
{
  const int b = blockIdx.x;
  const int t = threadIdx.x;
  const int w = t >> 6;
  const int l = t & 63;

  __shared__ __align__(16) _Float16 h2[2][256];

  const u32x4v* wp4 = (const u32x4v*)wp;
  const int wbase = w * 6;

#define LBK(nt, ks) const u32x4v b##nt##_##ks = wp4[(((wbase + nt) * 8 + ks) << 6) + l];
#define LBNT(nt) LBK(nt,0) LBK(nt,1) LBK(nt,2) LBK(nt,3) \
                 LBK(nt,4) LBK(nt,5) LBK(nt,6) LBK(nt,7)
  LBNT(0) LBNT(1) LBNT(2) LBNT(3) LBNT(4) LBNT(5)
#undef LBNT
#undef LBK

  const int half = (l >> 4) & 1;
  const int j = 16 * w + (l & 15) + 128 * half;
  const bool act = (l < 32);
  float br = 0.f, bz = 0.f, bn = 0.f;
  float hold = 0.f;
  if (act) { br = bhh[j]; bz = bhh[256 + j]; bn = bhh[512 + j]; }
  if (t < 256) { h2[0][t] = (_Float16)0.f; h2[1][t] = (_Float16)0.f; }
  __syncthreads();

  const float* gib = gi + (size_t)b * 512 * 768;
  const char* h2c = (const char*)h2;
  const int g16 = (l >> 4) * 16;
  int cur = 0;

#pragma unroll 1
  for (int step = 0; step < 512; ++step) {
    float ir = 0.f, iz = 0.f, inn = 0.f;
    if (act) {
      const float* g = gib + (size_t)step * 768;
      ir = g[j]; iz = g[256 + j]; inn = g[512 + j];
    }

    f32x4 c0 = {0.f,0.f,0.f,0.f}, c1 = c0, c2 = c0, c3 = c0, c4 = c0, c5 = c0;

#define DOT_KS(ks) { \
    const u32x4v a = *(const u32x4v*)(h2c + cur * 512 + (ks) * 64 + g16); \
    MFMA_A(c0, a, b0_##ks); MFMA_A(c1, a, b1_##ks); MFMA_A(c2, a, b2_##ks); \
    MFMA_A(c3, a, b3_##ks); MFMA_A(c4, a, b4_##ks); MFMA_A(c5, a, b5_##ks); }
    DOT_KS(0) DOT_KS(1) DOT_KS(2) DOT_KS(3)
    DOT_KS(4) DOT_KS(5) DOT_KS(6) DOT_KS(7)
#undef DOT_KS
    asm volatile("s_nop 7\n\ts_nop 7");

    if (act) {
      const float cr = half ? c1.x : c0.x;
      const float cz = half ? c3.x : c2.x;
      const float cn = half ? c5.x : c4.x;
      const float r = __builtin_amdgcn_rcpf(1.f + __expf(-(ir + cr + br)));
      const float z = __builtin_amdgcn_rcpf(1.f + __expf(-(iz + cz + bz)));
      const float e2 = __expf(2.f * (inn + r * (cn + bn)));
      const float n = 1.f - 2.f * __builtin_amdgcn_rcpf(e2 + 1.f);
      hold = (1.f - z) * n + z * hold;
      h2[cur ^ 1][j] = (_Float16)hold;
      const size_t rowi = (size_t)b * 512 + step;
      if (WF16) {
        const _Float16 hh = (_Float16)hold;
        ysh[rowi * 256 + j] = hh;
        ysl[rowi * 256 + j] = (_Float16)(hold - (float)hh);
      }
      if (LASTONLY) {
        if (step == 511) ys[rowi * 256 + j] = hold;
      }
    }
    GRU_BARRIER();
    cur ^= 1;
  }
}

// ------------------------------------------------------------------ FC head
__global__ __launch_bounds__(128) void k_head(
    const float* __restrict__ ys1,
    const float* __restrict__ fc1w, const float* __restrict__ fc1b,
    const float* __restrict__ fc2w, const float* __restrict__ fc2b,
    float* __restrict__ out)
{
  __shared__ float last[256];
  __shared__ float o1[128];
  const int b = blockIdx.x, t = threadIdx.x;
  const float* src = ys1 + (size_t)(b * 512 + 511) * 256;
  last[t] = src[t];
  last[128 + t] = src[128 + t];
  __syncthreads();
  float acc = fc1b[t];
#pragma unroll 8
  for (int k = 0; k < 256; ++k) acc += last[k] * fc1w[k * 128 + t];
  o1[t] = fmaxf(acc, 0.f);
  __syncthreads();
  if (t < 64) {
    float acc2 = fc2b[t];
#pragma unroll 8
    for (int i = 0; i < 128; ++i) acc2 += o1[i] * fc2w[i * 64 + t];
    out[b * 64 + t] = acc2;
  }
}

// ------------------------------------------------------------------ launcher
extern "C" void kernel_launch(void* const* d_in, const int* in_sizes, int n_in,
                              void* d_out, int out_size, void* d_ws, size_t ws_size,
                              hipStream_t stream)
{
  const float* x    = (const float*)d_in[0];
  const float* adj  = (const float*)d_in[1];
  const float* W0   = (const float*)d_in[2];
  const float* b0   = (const float*)d_in[3];
  const float* W1   = (const float*)d_in[4];
  const float* b1   = (const float*)d_in[5];
  const float* bng  = (const float*)d_in[6];
  const float* bnbb = (const float*)d_in[7];
  const float* bnm  = (const float*)d_in[8];
  const float* bnv  = (const float*)d_in[9];
  const float* Wih0 = (const float*)d_in[10];
  const float* Whh0 = (const float*)d_in[11];
  const float* bih0 = (const float*)d_in[12];
  const float* bhh0 = (const float*)d_in[13];
  const float* Wih1 = (const float*)d_in[14];
  const float* Whh1 = (const float*)d_in[15];
  const float* bih1 = (const float*)d_in[16];
  const float* bhh1 = (const float*)d_in[17];
  const float* fc1w = (const float*)d_in[18];
  const float* fc1b = (const float*)d_in[19];
  const float* fc2w = (const float*)d_in[20];
  const float* fc2b = (const float*)d_in[21];
  float* out = (float*)d_out;

  float* ws = (float*)d_ws;
  const size_t fixed = (size_t)16384 * 768 + (size_t)16384 * 256
                     + 2 * ((size_t)16384 * 128)
                     + 2 * 98304
                     + 2 * ((size_t)768 * 4096 / 2)
                     + 2 * ((size_t)768 * 256 / 2)
                     + 4 * 2048;
  int CHUNK = 16384;
  while (CHUNK > 128 && ((size_t)CHUNK * 4096 + fixed) * 4 > ws_size) CHUNK >>= 1;

  size_t off = 0;
  _Float16* seqh = (_Float16*)(ws + off); off += (size_t)CHUNK * 2048;
  _Float16* seql = (_Float16*)(ws + off); off += (size_t)CHUNK * 2048;
  float* gi      = ws + off; off += (size_t)16384 * 768;
  float* ys1     = ws + off; off += (size_t)16384 * 256;
  _Float16* ysh  = (_Float16*)(ws + off); off += (size_t)16384 * 128;
  _Float16* ysl  = (_Float16*)(ws + off); off += (size_t)16384 * 128;
  uint4* wp0     = (uint4*)(ws + off); off += 98304;
  uint4* wp1     = (uint4*)(ws + off); off += 98304;
  _Float16* bh0  = (_Float16*)(ws + off); off += (size_t)768 * 2048;
  _Float16* bl0  = (_Float16*)(ws + off); off += (size_t)768 * 2048;
  _Float16* bh1  = (_Float16*)(ws + off); off += (size_t)768 * 128;
  _Float16* bl1  = (_Float16*)(ws + off); off += (size_t)768 * 128;
  uint4* adjFh   = (uint4*)(ws + off); off += 2048;
  uint4* adjFl   = (uint4*)(ws + off); off += 2048;
  uint4* w1Fh    = (uint4*)(ws + off); off += 2048;
  uint4* w1Fl    = (uint4*)(ws + off); off += 2048;

  k_pack_frag<<<96, 256, 0, stream>>>(Whh0, wp0);
  k_pack_frag<<<96, 256, 0, stream>>>(Whh1, wp1);
  k_pack_gcn<<<4, 256, 0, stream>>>(adj, W1, adjFh, adjFl, w1Fh, w1Fl);
  k_split16<<<(3145728 + 255) / 256, 256, 0, stream>>>(Wih0, bh0, bl0, 3145728);
  k_split16<<<(196608 + 255) / 256, 256, 0, stream>>>(Wih1, bh1, bl1, 196608);

  const int nChunks = 16384 / CHUNK;
  for (int ci = 0; ci < nChunks; ++ci) {
    const int base = ci * CHUNK;
    k_gcn<<<CHUNK, 256, 0, stream>>>(x, adj, W0, b0, adjFh, adjFl, w1Fh, w1Fl,
                                     b1, bng, bnbb, bnm, bnv, seqh, seql, base);
    const int mB = CHUNK / 128;
    k_gemm_lds<<<mB * 6, 256, 0, stream>>>(seqh, seql, bh0, bl0, bih0,
                                           gi + (size_t)base * 768, 4096, mB);
  }
  // GRU0: emits f16 hi/lo every step (consumed by gi1 GEMM)
  k_gru<true, false><<<32, 512, 0, stream>>>(gi, wp0, bhh0, nullptr, ysh, ysl);
  k_gemm_lds<<<128 * 6, 256, 0, stream>>>(ysh, ysl, bh1, bl1, bih1, gi, 256, 128);
  // GRU1: emits fp32 at step 511 only (consumed by head)
  k_gru<false, true><<<32, 512, 0, stream>>>(gi, wp1, bhh1, ys1, nullptr, nullptr);
  k_head<<<32, 128, 0, stream>>>(ys1, fc1w, fc1b, fc2w, fc2b, out);
}